// Round 19
// baseline (134.439 us; speedup 1.0000x reference)
//
#include <hip/hip_runtime.h>
#include <hip/hip_bf16.h>
#include <math.h>

typedef unsigned short u16;
typedef __attribute__((ext_vector_type(8))) __bf16 bf16x8;
typedef __attribute__((ext_vector_type(4))) float f32x4;
typedef __attribute__((ext_vector_type(8))) unsigned short u16x8;
typedef __attribute__((ext_vector_type(4))) unsigned int u32x4;

// ---------- helpers ----------
__device__ __forceinline__ u16 f2bf(float f) {
  union { float f; unsigned u; } x; x.f = f;
  unsigned r = x.u + 0x7fffu + ((x.u >> 16) & 1u);   // RNE
  return (u16)(r >> 16);
}

__device__ __forceinline__ void gload16(const u16* g, u16* l) {
  __builtin_amdgcn_global_load_lds(
      (const __attribute__((address_space(1))) void*)g,
      (__attribute__((address_space(3))) void*)l, 16, 0, 0);
}

#define MFMA16(a, b, c) __builtin_amdgcn_mfma_f32_16x16x32_bf16((a), (b), (c), 0, 0, 0)

// Q pre-scale: 1/sqrt(64) * log2(e)  (softmax done in exp2 domain)
#define QSCALE 0.18033688011112043f

// ---------- merged cast fp32 -> bf16 (x, Wqkv, Wo in one launch) ----------
__global__ __launch_bounds__(256) void cast_all_kernel(
    const float* __restrict__ x, const float* __restrict__ wqkv,
    const float* __restrict__ wo, u16* __restrict__ xb,
    u16* __restrict__ wqb, u16* __restrict__ wob) {
  int i = blockIdx.x * 256 + threadIdx.x;   // in float4 units
  const float* src; u16* dst;
  if (i < 1048576)      { src = x;    dst = xb;  }
  else if (i < 1835008) { src = wqkv; dst = wqb; i -= 1048576; }
  else                  { src = wo;   dst = wob; i -= 1835008; }
  f32x4 v = *(const f32x4*)(src + (size_t)i * 4);
  u16 o0 = f2bf(v[0]), o1 = f2bf(v[1]), o2 = f2bf(v[2]), o3 = f2bf(v[3]);
  unsigned lo = (unsigned)o0 | ((unsigned)o1 << 16);
  unsigned hi = (unsigned)o2 | ((unsigned)o3 << 16);
  ((unsigned*)dst)[(size_t)i * 2] = lo;
  ((unsigned*)dst)[(size_t)i * 2 + 1] = hi;
}

// ---------- GEMM1: 256x256 tile, BK=64, 8 waves, 8-phase counted-vmcnt ----------
// 3-bit LDS swizzle (attn-proven form): source kg ^= (row&7); reads use
// kg = (kk*4+g) ^ (q15&7) since all read rows have row&7 == q15&7.
// Also zeroes the attn work-steal counter (stream-ordered before attn).
__global__ __launch_bounds__(512, 2) void gemm_qkv_kernel(
    const u16* __restrict__ X, const u16* __restrict__ W, const float* __restrict__ bias,
    u16* __restrict__ Qb, u16* __restrict__ Kb, u16* __restrict__ V2,
    unsigned* __restrict__ cnt) {
  if (blockIdx.x == 0 && blockIdx.y == 0 && threadIdx.x == 0) *cnt = 0u;
  __shared__ __align__(16) u16 As[2][2][128 * 64];   // [dbuf][mhalf][row*64+k]
  __shared__ __align__(16) u16 Bs[2][2][128 * 64];   // [dbuf][nhalf][row*64+k]
  const int tid = threadIdx.x;
  const int lane = tid & 63;
  const int wid = tid >> 6;
  const int wm = wid >> 2, wn = wid & 3;          // 2M x 4N wave grid
  const int g = lane >> 4, q15 = lane & 15;
  const int m0b = blockIdx.y * 256;
  const int n0b = blockIdx.x * 256;
  const int sA = q15 & 7;                         // read-side 3-bit k-group XOR

  auto stageA = [&](int kt, int h) {
    #pragma unroll
    for (int it = 0; it < 2; ++it) {
      int c = it * 512 + tid;
      int row = c >> 3, kg = c & 7;
      int kgs = kg ^ (row & 7);                   // pre-swizzled SOURCE
      gload16(X + (size_t)(m0b + h * 128 + row) * 1024 + kt * 64 + kgs * 8,
              &As[kt & 1][h][c * 8]);             // linear LDS dest
    }
  };
  auto stageB = [&](int kt, int h) {
    #pragma unroll
    for (int it = 0; it < 2; ++it) {
      int c = it * 512 + tid;
      int row = c >> 3, kg = c & 7;
      int kgs = kg ^ (row & 7);
      gload16(W + (size_t)(n0b + h * 128 + row) * 1024 + kt * 64 + kgs * 8,
              &Bs[kt & 1][h][c * 8]);
    }
  };

  f32x4 acc[8][4] = {};

  // ---- prologue: A(0), B(0), B(1); wait leaves B(1) in flight ----
  stageA(0, 0); stageA(0, 1);
  stageB(0, 0); stageB(0, 1);
  stageB(1, 0); stageB(1, 1);
  asm volatile("s_waitcnt vmcnt(4)" ::: "memory");
  __builtin_amdgcn_s_barrier();

  for (int kt = 0; kt < 16; ++kt) {
    const int d = kt & 1;
    const u16* Ah = As[d][wm];
    const u16* Bh = Bs[d][wn >> 1];
    const int rB0 = (wn & 1) * 64;
    bf16x8 bfr[4][2];
    #pragma unroll
    for (int q = 0; q < 4; ++q) {
      bf16x8 afr[2][2];
      if (q == 0) {                               // 8 B-frags, held across phases
        #pragma unroll
        for (int n = 0; n < 4; ++n)
          #pragma unroll
          for (int kk = 0; kk < 2; ++kk) {
            int row = rB0 + n * 16 + q15;
            int kg = (kk * 4 + g) ^ sA;
            bfr[n][kk] = *(const bf16x8*)(Bh + row * 64 + kg * 8);
          }
      }
      #pragma unroll
      for (int p = 0; p < 2; ++p)
        #pragma unroll
        for (int kk = 0; kk < 2; ++kk) {
          int row = (2 * q + p) * 16 + q15;
          int kg = (kk * 4 + g) ^ sA;
          afr[p][kk] = *(const bf16x8*)(Ah + row * 64 + kg * 8);
        }
      // stage one half-tile per phase
      if (q == 0)      { if (kt + 1 < 16) stageA(kt + 1, 0); }
      else if (q == 1) { if (kt + 1 < 16) stageA(kt + 1, 1); }
      else if (q == 2) { if (kt + 2 < 16) stageB(kt + 2, 0); }
      else             { if (kt + 2 < 16) stageB(kt + 2, 1); }
      __builtin_amdgcn_s_barrier();
      asm volatile("s_waitcnt lgkmcnt(0)" ::: "memory");
      __builtin_amdgcn_sched_barrier(0);
      __builtin_amdgcn_s_setprio(1);
      #pragma unroll
      for (int kk = 0; kk < 2; ++kk)
        #pragma unroll
        for (int p = 0; p < 2; ++p)
          #pragma unroll
          for (int n = 0; n < 4; ++n)
            acc[2 * q + p][n] = MFMA16(afr[p][kk], bfr[n][kk], acc[2 * q + p][n]);
      __builtin_amdgcn_s_setprio(0);
      if (q == 3) {                               // counted boundary wait
        if (kt < 14)       asm volatile("s_waitcnt vmcnt(4)" ::: "memory");
        else if (kt == 14) asm volatile("s_waitcnt vmcnt(0)" ::: "memory");
      }
      __builtin_amdgcn_s_barrier();
    }
  }

  const int which = n0b >> 10;                    // 0=Q 1=K 2=V (block-uniform)

  if (which < 2) {
    // ---- Q/K epilogue: bias (+Q-scale), direct scatter to [B,nh,C,64] ----
    const float qs = (which == 0) ? QSCALE : 1.0f;
    u16* __restrict__ dst = (which == 0) ? Qb : Kb;
    #pragma unroll
    for (int n = 0; n < 4; ++n) {
      int gcol = n0b + wn * 64 + n * 16 + q15;
      float bz = bias[gcol];
      int h = (gcol >> 6) & 15, d0 = gcol & 63;
      #pragma unroll
      for (int m = 0; m < 8; ++m)
        #pragma unroll
        for (int j = 0; j < 4; ++j) {
          int grow = m0b + wm * 128 + m * 16 + g * 4 + j;
          int bb = grow >> 11, qq = grow & 2047;
          dst[((size_t)((bb * 16 + h) * 2048 + qq)) * 64 + d0] =
              f2bf((acc[m][n][j] + bz) * qs);
        }
    }
  } else {
    // ---- V epilogue: 2-pass LDS transpose -> V2 [head][tile][d][key] ----
    u16* Ct = &As[0][0][0];                       // 64KB: [col 128][row 256]
    #pragma unroll
    for (int half = 0; half < 2; ++half) {
      __syncthreads();
      if ((wn >> 1) == half) {
        #pragma unroll
        for (int n = 0; n < 4; ++n) {
          int c = (wn & 1) * 64 + n * 16 + q15;   // col within half
          float bz = bias[n0b + half * 128 + c];
          #pragma unroll
          for (int m = 0; m < 8; ++m)
            #pragma unroll
            for (int j = 0; j < 4; ++j) {
              int r = wm * 128 + m * 16 + g * 4 + j;
              Ct[c * 256 + (r ^ ((c & 15) << 3))] = f2bf(acc[m][n][j] + bz);
            }
        }
      }
      __syncthreads();
      #pragma unroll
      for (int i = 0; i < 8; ++i) {
        int chunk = i * 512 + tid;
        int cc = chunk >> 5;                      // 0..127 (col within half)
        int r0 = (chunk & 31) * 8;                // 0..248
        u16x8 val = *(const u16x8*)(Ct + cc * 256 + (r0 ^ ((cc & 15) << 3)));
        int gcol = n0b + half * 128 + cc;
        int h = (gcol >> 6) & 15, d0 = gcol & 63;
        int grow = m0b + r0;
        int bb = grow >> 11, qq = grow & 2047;
        int tt = qq >> 6, key = qq & 63;
        *(u16x8*)(V2 + ((((size_t)(bb * 16 + h) * 32 + tt) * 64 + d0) * 64 + key)) = val;
      }
    }
  }
}

// ---------- GEMM2: out = attn @ Wo^T + b (fp32), 64x128 tile, dbuf 1-barrier ----------
__global__ __launch_bounds__(256) void gemm_out_kernel(
    const u16* __restrict__ Ain, const u16* __restrict__ W, const float* __restrict__ bias,
    float* __restrict__ out) {
  __shared__ __align__(16) u16 As[2][64 * 64];
  __shared__ __align__(16) u16 Bs[2][128 * 64];
  const int tid = threadIdx.x;
  const int lane = tid & 63;
  const int wc = tid >> 6;                 // wave -> 32-col group
  const int m0 = blockIdx.y * 64;
  const int n0 = blockIdx.x * 128;

  auto stage = [&](int k0, int buf) {
    #pragma unroll
    for (int it = 0; it < 2; ++it) {
      int c = it * 256 + tid;
      gload16(Ain + (size_t)(m0 + (c >> 3)) * 1024 + k0 + ((c & 7) << 3),
              As[buf] + c * 8);
    }
    #pragma unroll
    for (int it = 0; it < 4; ++it) {
      int c = it * 256 + tid;
      gload16(W + (size_t)(n0 + (c >> 3)) * 1024 + k0 + ((c & 7) << 3),
              Bs[buf] + c * 8);
    }
  };

  f32x4 acc[4][2] = {};
  stage(0, 0);
  __syncthreads();
  for (int k0 = 0; k0 < 1024; k0 += 64) {
    const int cur = (k0 >> 6) & 1;
    if (k0 + 64 < 1024) stage(k0 + 64, cur ^ 1);   // issue-early; overlaps compute
    #pragma unroll
    for (int kk = 0; kk < 2; ++kk) {
      bf16x8 a[4], b[2];
      #pragma unroll
      for (int m = 0; m < 4; ++m)
        a[m] = *(const bf16x8*)(As[cur] + ((m * 16 + (lane & 15)) * 64 +
                                           kk * 32 + ((lane >> 4) << 3)));
      #pragma unroll
      for (int n = 0; n < 2; ++n)
        b[n] = *(const bf16x8*)(Bs[cur] + ((wc * 32 + n * 16 + (lane & 15)) * 64 +
                                           kk * 32 + ((lane >> 4) << 3)));
      __builtin_amdgcn_s_setprio(1);
      #pragma unroll
      for (int m = 0; m < 4; ++m)
        #pragma unroll
        for (int n = 0; n < 2; ++n)
          acc[m][n] = MFMA16(a[m], b[n], acc[m][n]);
      __builtin_amdgcn_s_setprio(0);
    }
    __syncthreads();   // drains next-stage DMA (issued before compute)
  }
  #pragma unroll
  for (int m = 0; m < 4; ++m)
    #pragma unroll
    for (int n = 0; n < 2; ++n)
      #pragma unroll
      for (int j = 0; j < 4; ++j) {
        int row = m0 + m * 16 + ((lane >> 4) << 2) + j;
        int col = n0 + wc * 32 + n * 16 + (lane & 15);
        out[(size_t)row * 1024 + col] = acc[m][n][j] + bias[col];
      }
}

// ---------- causal flash attention: swapped-QK^T, in-register softmax & P ----------
// r17/r18-verified body (61.5 us): V from V2 [d][key] subtiles via K-style path.
__device__ __forceinline__ void attn_one(
    const u16* __restrict__ Qh, const u16* __restrict__ Kh, const u16* __restrict__ V2h,
    u16* __restrict__ Ob, int bb, int h, int qt,
    u16 (*Ks)[64 * 64], u16 (*Vs)[64 * 64]) {
  const int tid = threadIdx.x, lane = tid & 63, w = tid >> 6;
  const int g = lane >> 4, q15 = lane & 15;

  // Q fragment (B-operand): lane holds Q[qrow][kk*32 + 8g + i]
  bf16x8 qf[2];
  const int qrow = qt * 64 + w * 16 + q15;
  #pragma unroll
  for (int kk = 0; kk < 2; ++kk)
    qf[kk] = *(const bf16x8*)(Qh + (size_t)qrow * 64 + kk * 32 + g * 8);

  f32x4 acc_o[4];
  #pragma unroll
  for (int n = 0; n < 4; ++n) acc_o[n] = (f32x4){0.f, 0.f, 0.f, 0.f};
  float m_run = -INFINITY, l_run = 0.f;

  const int nt = qt + 1;

  auto stageK = [&](int t, int buf) {
    #pragma unroll
    for (int it = 0; it < 2; ++it) {
      int c = it * 256 + tid;
      int row = c >> 3, b8 = c & 7;
      gload16(Kh + (size_t)(t * 64 + row) * 64 + ((b8 ^ (row & 7)) << 3),
              Ks[buf] + c * 8);
    }
  };
  auto stageV = [&](int t, int buf) {    // V2: per-tile [d=64][key=64] contiguous
    #pragma unroll
    for (int it = 0; it < 2; ++it) {
      int c = it * 256 + tid;
      int row = c >> 3, b8 = c & 7;      // row = d
      gload16(V2h + (size_t)t * 4096 + row * 64 + ((b8 ^ (row & 7)) << 3),
              Vs[buf] + c * 8);
    }
  };

  // ---- prologue: tile 0 ----
  stageK(0, 0);
  stageV(0, 0);
  __syncthreads();

  for (int t = 0; t < nt; ++t) {
    const int cur = t & 1;
    const bool pre = (t + 1 < nt);
    if (pre) { stageK(t + 1, cur ^ 1); stageV(t + 1, cur ^ 1); }

    // ---- ST = K @ Q^T : lane holds P[q=q15][key = 16cb + 4g + j] ----
    f32x4 accs[4];
    __builtin_amdgcn_s_setprio(1);
    #pragma unroll
    for (int cb = 0; cb < 4; ++cb) {
      accs[cb] = (f32x4){0.f, 0.f, 0.f, 0.f};
      #pragma unroll
      for (int kk = 0; kk < 2; ++kk) {
        int row = cb * 16 + q15;
        int kblk = kk * 4 + g;
        bf16x8 kf = *(const bf16x8*)(Ks[cur] + row * 64 + ((kblk ^ (row & 7)) << 3));
        accs[cb] = MFMA16(kf, qf[kk], accs[cb]);
      }
    }
    __builtin_amdgcn_s_setprio(0);
    // causal mask on diagonal tile
    if (t == nt - 1) {
      #pragma unroll
      for (int cb = 0; cb < 4; ++cb)
        #pragma unroll
        for (int j = 0; j < 4; ++j) {
          int kg = t * 64 + cb * 16 + 4 * g + j;
          if (kg > qrow) accs[cb][j] = -INFINITY;
        }
    }

    // ---- online softmax (exp2 domain), lane-local q-row, T13 defer-max ----
    float mj = accs[0][0];
    #pragma unroll
    for (int cb = 0; cb < 4; ++cb)
      #pragma unroll
      for (int j = 0; j < 4; ++j) mj = fmaxf(mj, accs[cb][j]);
    mj = fmaxf(mj, __shfl_xor(mj, 16));
    mj = fmaxf(mj, __shfl_xor(mj, 32));
    if (!__all(mj - m_run <= 8.0f)) {
      float mn = fmaxf(m_run, mj);
      float sc = exp2f(m_run - mn);
      m_run = mn;
      l_run *= sc;
      float scj[4];
      #pragma unroll
      for (int j = 0; j < 4; ++j) scj[j] = __shfl(sc, 4 * g + j);
      #pragma unroll
      for (int n = 0; n < 4; ++n)
        #pragma unroll
        for (int j = 0; j < 4; ++j) acc_o[n][j] *= scj[j];
    }
    float rs = 0.f;
    #pragma unroll
    for (int cb = 0; cb < 4; ++cb)
      #pragma unroll
      for (int j = 0; j < 4; ++j) {
        float p = exp2f(accs[cb][j] - m_run);
        accs[cb][j] = p;
        rs += p;
      }
    rs += __shfl_xor(rs, 16);
    rs += __shfl_xor(rs, 32);
    l_run += rs;

    // ---- pack P to bf16 pairs: Wp[cb][hh] = keys (16cb+4g+2hh, +1) ----
    unsigned Wp[4][2];
    #pragma unroll
    for (int cb = 0; cb < 4; ++cb)
      #pragma unroll
      for (int hh = 0; hh < 2; ++hh)
        asm("v_cvt_pk_bf16_f32 %0, %1, %2"
            : "=v"(Wp[cb][hh]) : "v"(accs[cb][2 * hh]), "v"(accs[cb][2 * hh + 1]));

    // ---- exchange into PV A-fragments: lane needs keys kk*32+8g..+7 ----
    unsigned aw[2][4];
    #pragma unroll
    for (int kk = 0; kk < 2; ++kk)
      #pragma unroll
      for (int iw = 0; iw < 4; ++iw) {
        int srcLane = q15 + ((((g & 1) << 1) + (iw >> 1)) << 4);
        unsigned c0 = __shfl(Wp[2 * kk + 0][iw & 1], srcLane);
        unsigned c1 = __shfl(Wp[2 * kk + 1][iw & 1], srcLane);
        aw[kk][iw] = (g >> 1) ? c1 : c0;
      }
    bf16x8 pa0 = __builtin_bit_cast(bf16x8, (u32x4){aw[0][0], aw[0][1], aw[0][2], aw[0][3]});
    bf16x8 pa1 = __builtin_bit_cast(bf16x8, (u32x4){aw[1][0], aw[1][1], aw[1][2], aw[1][3]});

    // ---- O += P @ V  (V via K-style swizzled ds_read_b128 from V2 tile) ----
    __builtin_amdgcn_s_setprio(1);
    #pragma unroll
    for (int n = 0; n < 4; ++n) {
      #pragma unroll
      for (int kk = 0; kk < 2; ++kk) {
        int d = n * 16 + q15;
        int kblk = kk * 4 + g;
        bf16x8 vb = *(const bf16x8*)(Vs[cur] + d * 64 + ((kblk ^ (d & 7)) << 3));
        acc_o[n] = MFMA16(kk ? pa1 : pa0, vb, acc_o[n]);
      }
    }
    __builtin_amdgcn_s_setprio(0);
    __syncthreads();
  }

  // ---- epilogue: O /= l, write bf16 to [B*C, H] ----
  float invl = 1.0f / l_run;
  float invj[4];
  #pragma unroll
  for (int j = 0; j < 4; ++j) invj[j] = __shfl(invl, 4 * g + j);
  #pragma unroll
  for (int n = 0; n < 4; ++n)
    #pragma unroll
    for (int j = 0; j < 4; ++j) {
      int qg = qt * 64 + w * 16 + 4 * g + j;
      Ob[((size_t)(bb * 2048 + qg)) * 1024 + h * 64 + n * 16 + q15] =
          f2bf(acc_o[n][j] * invj[j]);
    }
}

// LPT work-steal: 1024 (head,qt) units longest-first; grid 768 < units so
// stealing balances; 3 blocks/CU x 4 waves (LDS 32KB, VGPR 48).
__global__ __launch_bounds__(256, 4) void attn_kernel(
    const u16* __restrict__ Qb, const u16* __restrict__ Kb, const u16* __restrict__ V2b,
    u16* __restrict__ Ob, unsigned* __restrict__ cnt) {
  __shared__ __align__(16) u16 Ks[2][64 * 64];
  __shared__ __align__(16) u16 Vs[2][64 * 64];
  __shared__ unsigned s_unit;
  for (;;) {
    if (threadIdx.x == 0) s_unit = atomicAdd(cnt, 1u);
    __syncthreads();
    unsigned u = s_unit;
    if (u >= 1024u) return;
    const int qt = 31 - (int)(u >> 5);   // longest-first
    const int bh = (int)(u & 31u);
    const size_t base = (size_t)bh * 2048 * 64;   // same stride for K and V2
    attn_one(Qb + base, Kb + base, V2b + base, Ob, bh >> 4, bh & 15, qt, Ks, Vs);
    __syncthreads();
  }
}

// ---------- launch ----------
extern "C" void kernel_launch(void* const* d_in, const int* in_sizes, int n_in,
                              void* d_out, int out_size, void* d_ws, size_t ws_size,
                              hipStream_t stream) {
  const float* x    = (const float*)d_in[0];   // [2,2048,1024]
  const float* wqkv = (const float*)d_in[1];   // [3072,1024]
  const float* bqkv = (const float*)d_in[2];   // [3072]
  const float* wo   = (const float*)d_in[3];   // [1024,1024]
  const float* bo   = (const float*)d_in[4];   // [1024]
  float* out = (float*)d_out;                  // [4096,1024] fp32

  const size_t MB = 1u << 20;
  char* ws = (char*)d_ws;
  u16* x_bf  = (u16*)(ws);             // 8 MB
  u16* wq_bf = (u16*)(ws + 8 * MB);    // 6 MB
  u16* wo_bf = (u16*)(ws + 14 * MB);   // 2 MB
  u16* q_buf = (u16*)(ws + 16 * MB);   // 8 MB  [B,nh,C,64]
  u16* k_buf = (u16*)(ws + 24 * MB);   // 8 MB  [B,nh,C,64]
  u16* v2_buf= (u16*)(ws + 32 * MB);   // 8 MB  [B,nh,tile32,d64,key64]
  u16* a_out = (u16*)(ws + 40 * MB);   // 8 MB  [4096,1024]

  // work-steal counter: last 4 bytes of d_out (scratch until gemm_out
  // fully rewrites d_out afterwards); zeroed by gemm_qkv each launch.
  unsigned* cnt = (unsigned*)((char*)d_out + (size_t)out_size * 4 - 4);

  cast_all_kernel<<<8192, 256, 0, stream>>>(x, wqkv, wo, x_bf, wq_bf, wo_bf);

  gemm_qkv_kernel<<<dim3(12, 16), 512, 0, stream>>>(x_bf, wq_bf, bqkv,
                                                    q_buf, k_buf, v2_buf, cnt);
  attn_kernel<<<768, 256, 0, stream>>>(q_buf, k_buf, v2_buf, a_out, cnt);
  gemm_out_kernel<<<dim3(8, 64), 256, 0, stream>>>(a_out, wo_bf, bo, out);
}

// Round 20
// 131.800 us; speedup vs baseline: 1.0200x; 1.0200x over previous
//
#include <hip/hip_runtime.h>
#include <hip/hip_bf16.h>
#include <math.h>

typedef unsigned short u16;
typedef __attribute__((ext_vector_type(8))) __bf16 bf16x8;
typedef __attribute__((ext_vector_type(4))) float f32x4;
typedef __attribute__((ext_vector_type(8))) unsigned short u16x8;
typedef __attribute__((ext_vector_type(4))) unsigned int u32x4;

// ---------- helpers ----------
__device__ __forceinline__ u16 f2bf(float f) {
  union { float f; unsigned u; } x; x.f = f;
  unsigned r = x.u + 0x7fffu + ((x.u >> 16) & 1u);   // RNE
  return (u16)(r >> 16);
}

__device__ __forceinline__ void gload16(const u16* g, u16* l) {
  __builtin_amdgcn_global_load_lds(
      (const __attribute__((address_space(1))) void*)g,
      (__attribute__((address_space(3))) void*)l, 16, 0, 0);
}

#define MFMA16(a, b, c) __builtin_amdgcn_mfma_f32_16x16x32_bf16((a), (b), (c), 0, 0, 0)

// Q pre-scale: 1/sqrt(64) * log2(e)  (softmax done in exp2 domain)
#define QSCALE 0.18033688011112043f

// ---------- merged cast fp32 -> bf16 (x, Wqkv, Wo in one launch) ----------
__global__ __launch_bounds__(256) void cast_all_kernel(
    const float* __restrict__ x, const float* __restrict__ wqkv,
    const float* __restrict__ wo, u16* __restrict__ xb,
    u16* __restrict__ wqb, u16* __restrict__ wob) {
  int i = blockIdx.x * 256 + threadIdx.x;   // in float4 units
  const float* src; u16* dst;
  if (i < 1048576)      { src = x;    dst = xb;  }
  else if (i < 1835008) { src = wqkv; dst = wqb; i -= 1048576; }
  else                  { src = wo;   dst = wob; i -= 1835008; }
  f32x4 v = *(const f32x4*)(src + (size_t)i * 4);
  u16 o0 = f2bf(v[0]), o1 = f2bf(v[1]), o2 = f2bf(v[2]), o3 = f2bf(v[3]);
  unsigned lo = (unsigned)o0 | ((unsigned)o1 << 16);
  unsigned hi = (unsigned)o2 | ((unsigned)o3 << 16);
  ((unsigned*)dst)[(size_t)i * 2] = lo;
  ((unsigned*)dst)[(size_t)i * 2 + 1] = hi;
}

// ---------- GEMM1: 256x256 tile, BK=64, 8 waves, 8-phase counted-vmcnt ----------
// 3-bit LDS swizzle (attn-proven form): source kg ^= (row&7); reads use
// kg = (kk*4+g) ^ (q15&7) since all read rows have row&7 == q15&7.
__global__ __launch_bounds__(512, 2) void gemm_qkv_kernel(
    const u16* __restrict__ X, const u16* __restrict__ W, const float* __restrict__ bias,
    u16* __restrict__ Qb, u16* __restrict__ Kb, u16* __restrict__ V2) {
  __shared__ __align__(16) u16 As[2][2][128 * 64];   // [dbuf][mhalf][row*64+k]
  __shared__ __align__(16) u16 Bs[2][2][128 * 64];   // [dbuf][nhalf][row*64+k]
  const int tid = threadIdx.x;
  const int lane = tid & 63;
  const int wid = tid >> 6;
  const int wm = wid >> 2, wn = wid & 3;          // 2M x 4N wave grid
  const int g = lane >> 4, q15 = lane & 15;
  const int m0b = blockIdx.y * 256;
  const int n0b = blockIdx.x * 256;
  const int sA = q15 & 7;                         // read-side 3-bit k-group XOR

  auto stageA = [&](int kt, int h) {
    #pragma unroll
    for (int it = 0; it < 2; ++it) {
      int c = it * 512 + tid;
      int row = c >> 3, kg = c & 7;
      int kgs = kg ^ (row & 7);                   // pre-swizzled SOURCE
      gload16(X + (size_t)(m0b + h * 128 + row) * 1024 + kt * 64 + kgs * 8,
              &As[kt & 1][h][c * 8]);             // linear LDS dest
    }
  };
  auto stageB = [&](int kt, int h) {
    #pragma unroll
    for (int it = 0; it < 2; ++it) {
      int c = it * 512 + tid;
      int row = c >> 3, kg = c & 7;
      int kgs = kg ^ (row & 7);
      gload16(W + (size_t)(n0b + h * 128 + row) * 1024 + kt * 64 + kgs * 8,
              &Bs[kt & 1][h][c * 8]);
    }
  };

  f32x4 acc[8][4] = {};

  // ---- prologue: A(0), B(0), B(1); wait leaves B(1) in flight ----
  stageA(0, 0); stageA(0, 1);
  stageB(0, 0); stageB(0, 1);
  stageB(1, 0); stageB(1, 1);
  asm volatile("s_waitcnt vmcnt(4)" ::: "memory");
  __builtin_amdgcn_s_barrier();

  for (int kt = 0; kt < 16; ++kt) {
    const int d = kt & 1;
    const u16* Ah = As[d][wm];
    const u16* Bh = Bs[d][wn >> 1];
    const int rB0 = (wn & 1) * 64;
    bf16x8 bfr[4][2];
    #pragma unroll
    for (int q = 0; q < 4; ++q) {
      bf16x8 afr[2][2];
      if (q == 0) {                               // 8 B-frags, held across phases
        #pragma unroll
        for (int n = 0; n < 4; ++n)
          #pragma unroll
          for (int kk = 0; kk < 2; ++kk) {
            int row = rB0 + n * 16 + q15;
            int kg = (kk * 4 + g) ^ sA;
            bfr[n][kk] = *(const bf16x8*)(Bh + row * 64 + kg * 8);
          }
      }
      #pragma unroll
      for (int p = 0; p < 2; ++p)
        #pragma unroll
        for (int kk = 0; kk < 2; ++kk) {
          int row = (2 * q + p) * 16 + q15;
          int kg = (kk * 4 + g) ^ sA;
          afr[p][kk] = *(const bf16x8*)(Ah + row * 64 + kg * 8);
        }
      // stage one half-tile per phase
      if (q == 0)      { if (kt + 1 < 16) stageA(kt + 1, 0); }
      else if (q == 1) { if (kt + 1 < 16) stageA(kt + 1, 1); }
      else if (q == 2) { if (kt + 2 < 16) stageB(kt + 2, 0); }
      else             { if (kt + 2 < 16) stageB(kt + 2, 1); }
      __builtin_amdgcn_s_barrier();
      asm volatile("s_waitcnt lgkmcnt(0)" ::: "memory");
      __builtin_amdgcn_sched_barrier(0);
      __builtin_amdgcn_s_setprio(1);
      #pragma unroll
      for (int kk = 0; kk < 2; ++kk)
        #pragma unroll
        for (int p = 0; p < 2; ++p)
          #pragma unroll
          for (int n = 0; n < 4; ++n)
            acc[2 * q + p][n] = MFMA16(afr[p][kk], bfr[n][kk], acc[2 * q + p][n]);
      __builtin_amdgcn_s_setprio(0);
      if (q == 3) {                               // counted boundary wait
        if (kt < 14)       asm volatile("s_waitcnt vmcnt(4)" ::: "memory");
        else if (kt == 14) asm volatile("s_waitcnt vmcnt(0)" ::: "memory");
      }
      __builtin_amdgcn_s_barrier();
    }
  }

  const int which = n0b >> 10;                    // 0=Q 1=K 2=V (block-uniform)

  if (which < 2) {
    // ---- Q/K epilogue: bias (+Q-scale), direct scatter to [B,nh,C,64] ----
    const float qs = (which == 0) ? QSCALE : 1.0f;
    u16* __restrict__ dst = (which == 0) ? Qb : Kb;
    #pragma unroll
    for (int n = 0; n < 4; ++n) {
      int gcol = n0b + wn * 64 + n * 16 + q15;
      float bz = bias[gcol];
      int h = (gcol >> 6) & 15, d0 = gcol & 63;
      #pragma unroll
      for (int m = 0; m < 8; ++m)
        #pragma unroll
        for (int j = 0; j < 4; ++j) {
          int grow = m0b + wm * 128 + m * 16 + g * 4 + j;
          int bb = grow >> 11, qq = grow & 2047;
          dst[((size_t)((bb * 16 + h) * 2048 + qq)) * 64 + d0] =
              f2bf((acc[m][n][j] + bz) * qs);
        }
    }
  } else {
    // ---- V epilogue: 2-pass LDS transpose -> V2 [head][tile][d][key] ----
    u16* Ct = &As[0][0][0];                       // 64KB: [col 128][row 256]
    #pragma unroll
    for (int half = 0; half < 2; ++half) {
      __syncthreads();
      if ((wn >> 1) == half) {
        #pragma unroll
        for (int n = 0; n < 4; ++n) {
          int c = (wn & 1) * 64 + n * 16 + q15;   // col within half
          float bz = bias[n0b + half * 128 + c];
          #pragma unroll
          for (int m = 0; m < 8; ++m)
            #pragma unroll
            for (int j = 0; j < 4; ++j) {
              int r = wm * 128 + m * 16 + g * 4 + j;
              Ct[c * 256 + (r ^ ((c & 15) << 3))] = f2bf(acc[m][n][j] + bz);
            }
        }
      }
      __syncthreads();
      #pragma unroll
      for (int i = 0; i < 8; ++i) {
        int chunk = i * 512 + tid;
        int cc = chunk >> 5;                      // 0..127 (col within half)
        int r0 = (chunk & 31) * 8;                // 0..248
        u16x8 val = *(const u16x8*)(Ct + cc * 256 + (r0 ^ ((cc & 15) << 3)));
        int gcol = n0b + half * 128 + cc;
        int h = (gcol >> 6) & 15, d0 = gcol & 63;
        int grow = m0b + r0;
        int bb = grow >> 11, qq = grow & 2047;
        int tt = qq >> 6, key = qq & 63;
        *(u16x8*)(V2 + ((((size_t)(bb * 16 + h) * 32 + tt) * 64 + d0) * 64 + key)) = val;
      }
    }
  }
}

// ---------- GEMM2: out = attn @ Wo^T + b (fp32), 64x128 tile, dbuf 1-barrier ----------
__global__ __launch_bounds__(256) void gemm_out_kernel(
    const u16* __restrict__ Ain, const u16* __restrict__ W, const float* __restrict__ bias,
    float* __restrict__ out) {
  __shared__ __align__(16) u16 As[2][64 * 64];
  __shared__ __align__(16) u16 Bs[2][128 * 64];
  const int tid = threadIdx.x;
  const int lane = tid & 63;
  const int wc = tid >> 6;                 // wave -> 32-col group
  const int m0 = blockIdx.y * 64;
  const int n0 = blockIdx.x * 128;

  auto stage = [&](int k0, int buf) {
    #pragma unroll
    for (int it = 0; it < 2; ++it) {
      int c = it * 256 + tid;
      gload16(Ain + (size_t)(m0 + (c >> 3)) * 1024 + k0 + ((c & 7) << 3),
              As[buf] + c * 8);
    }
    #pragma unroll
    for (int it = 0; it < 4; ++it) {
      int c = it * 256 + tid;
      gload16(W + (size_t)(n0 + (c >> 3)) * 1024 + k0 + ((c & 7) << 3),
              Bs[buf] + c * 8);
    }
  };

  f32x4 acc[4][2] = {};
  stage(0, 0);
  __syncthreads();
  for (int k0 = 0; k0 < 1024; k0 += 64) {
    const int cur = (k0 >> 6) & 1;
    if (k0 + 64 < 1024) stage(k0 + 64, cur ^ 1);   // issue-early; overlaps compute
    #pragma unroll
    for (int kk = 0; kk < 2; ++kk) {
      bf16x8 a[4], b[2];
      #pragma unroll
      for (int m = 0; m < 4; ++m)
        a[m] = *(const bf16x8*)(As[cur] + ((m * 16 + (lane & 15)) * 64 +
                                           kk * 32 + ((lane >> 4) << 3)));
      #pragma unroll
      for (int n = 0; n < 2; ++n)
        b[n] = *(const bf16x8*)(Bs[cur] + ((wc * 32 + n * 16 + (lane & 15)) * 64 +
                                           kk * 32 + ((lane >> 4) << 3)));
      __builtin_amdgcn_s_setprio(1);
      #pragma unroll
      for (int m = 0; m < 4; ++m)
        #pragma unroll
        for (int n = 0; n < 2; ++n)
          acc[m][n] = MFMA16(a[m], b[n], acc[m][n]);
      __builtin_amdgcn_s_setprio(0);
    }
    __syncthreads();   // drains next-stage DMA (issued before compute)
  }
  #pragma unroll
  for (int m = 0; m < 4; ++m)
    #pragma unroll
    for (int n = 0; n < 2; ++n)
      #pragma unroll
      for (int j = 0; j < 4; ++j) {
        int row = m0 + m * 16 + ((lane >> 4) << 2) + j;
        int col = n0 + wc * 32 + n * 16 + (lane & 15);
        out[(size_t)row * 1024 + col] = acc[m][n][j] + bias[col];
      }
}

// ---------- causal flash attention: swapped-QK^T, in-register softmax & P ----------
// r17/r18-verified body (61.5 us): V from V2 [d][key] subtiles via K-style path.
__device__ __forceinline__ void attn_one(
    const u16* __restrict__ Qh, const u16* __restrict__ Kh, const u16* __restrict__ V2h,
    u16* __restrict__ Ob, int bb, int h, int qt,
    u16 (*Ks)[64 * 64], u16 (*Vs)[64 * 64]) {
  const int tid = threadIdx.x, lane = tid & 63, w = tid >> 6;
  const int g = lane >> 4, q15 = lane & 15;

  // Q fragment (B-operand): lane holds Q[qrow][kk*32 + 8g + i]
  bf16x8 qf[2];
  const int qrow = qt * 64 + w * 16 + q15;
  #pragma unroll
  for (int kk = 0; kk < 2; ++kk)
    qf[kk] = *(const bf16x8*)(Qh + (size_t)qrow * 64 + kk * 32 + g * 8);

  f32x4 acc_o[4];
  #pragma unroll
  for (int n = 0; n < 4; ++n) acc_o[n] = (f32x4){0.f, 0.f, 0.f, 0.f};
  float m_run = -INFINITY, l_run = 0.f;

  const int nt = qt + 1;

  auto stageK = [&](int t, int buf) {
    #pragma unroll
    for (int it = 0; it < 2; ++it) {
      int c = it * 256 + tid;
      int row = c >> 3, b8 = c & 7;
      gload16(Kh + (size_t)(t * 64 + row) * 64 + ((b8 ^ (row & 7)) << 3),
              Ks[buf] + c * 8);
    }
  };
  auto stageV = [&](int t, int buf) {    // V2: per-tile [d=64][key=64] contiguous
    #pragma unroll
    for (int it = 0; it < 2; ++it) {
      int c = it * 256 + tid;
      int row = c >> 3, b8 = c & 7;      // row = d
      gload16(V2h + (size_t)t * 4096 + row * 64 + ((b8 ^ (row & 7)) << 3),
              Vs[buf] + c * 8);
    }
  };

  // ---- prologue: tile 0 ----
  stageK(0, 0);
  stageV(0, 0);
  __syncthreads();

  for (int t = 0; t < nt; ++t) {
    const int cur = t & 1;
    const bool pre = (t + 1 < nt);
    if (pre) { stageK(t + 1, cur ^ 1); stageV(t + 1, cur ^ 1); }

    // ---- ST = K @ Q^T : lane holds P[q=q15][key = 16cb + 4g + j] ----
    f32x4 accs[4];
    __builtin_amdgcn_s_setprio(1);
    #pragma unroll
    for (int cb = 0; cb < 4; ++cb) {
      accs[cb] = (f32x4){0.f, 0.f, 0.f, 0.f};
      #pragma unroll
      for (int kk = 0; kk < 2; ++kk) {
        int row = cb * 16 + q15;
        int kblk = kk * 4 + g;
        bf16x8 kf = *(const bf16x8*)(Ks[cur] + row * 64 + ((kblk ^ (row & 7)) << 3));
        accs[cb] = MFMA16(kf, qf[kk], accs[cb]);
      }
    }
    __builtin_amdgcn_s_setprio(0);
    // causal mask on diagonal tile
    if (t == nt - 1) {
      #pragma unroll
      for (int cb = 0; cb < 4; ++cb)
        #pragma unroll
        for (int j = 0; j < 4; ++j) {
          int kg = t * 64 + cb * 16 + 4 * g + j;
          if (kg > qrow) accs[cb][j] = -INFINITY;
        }
    }

    // ---- online softmax (exp2 domain), lane-local q-row, T13 defer-max ----
    float mj = accs[0][0];
    #pragma unroll
    for (int cb = 0; cb < 4; ++cb)
      #pragma unroll
      for (int j = 0; j < 4; ++j) mj = fmaxf(mj, accs[cb][j]);
    mj = fmaxf(mj, __shfl_xor(mj, 16));
    mj = fmaxf(mj, __shfl_xor(mj, 32));
    if (!__all(mj - m_run <= 8.0f)) {
      float mn = fmaxf(m_run, mj);
      float sc = exp2f(m_run - mn);
      m_run = mn;
      l_run *= sc;
      float scj[4];
      #pragma unroll
      for (int j = 0; j < 4; ++j) scj[j] = __shfl(sc, 4 * g + j);
      #pragma unroll
      for (int n = 0; n < 4; ++n)
        #pragma unroll
        for (int j = 0; j < 4; ++j) acc_o[n][j] *= scj[j];
    }
    float rs = 0.f;
    #pragma unroll
    for (int cb = 0; cb < 4; ++cb)
      #pragma unroll
      for (int j = 0; j < 4; ++j) {
        float p = exp2f(accs[cb][j] - m_run);
        accs[cb][j] = p;
        rs += p;
      }
    rs += __shfl_xor(rs, 16);
    rs += __shfl_xor(rs, 32);
    l_run += rs;

    // ---- pack P to bf16 pairs: Wp[cb][hh] = keys (16cb+4g+2hh, +1) ----
    unsigned Wp[4][2];
    #pragma unroll
    for (int cb = 0; cb < 4; ++cb)
      #pragma unroll
      for (int hh = 0; hh < 2; ++hh)
        asm("v_cvt_pk_bf16_f32 %0, %1, %2"
            : "=v"(Wp[cb][hh]) : "v"(accs[cb][2 * hh]), "v"(accs[cb][2 * hh + 1]));

    // ---- exchange into PV A-fragments: lane needs keys kk*32+8g..+7 ----
    unsigned aw[2][4];
    #pragma unroll
    for (int kk = 0; kk < 2; ++kk)
      #pragma unroll
      for (int iw = 0; iw < 4; ++iw) {
        int srcLane = q15 + ((((g & 1) << 1) + (iw >> 1)) << 4);
        unsigned c0 = __shfl(Wp[2 * kk + 0][iw & 1], srcLane);
        unsigned c1 = __shfl(Wp[2 * kk + 1][iw & 1], srcLane);
        aw[kk][iw] = (g >> 1) ? c1 : c0;
      }
    bf16x8 pa0 = __builtin_bit_cast(bf16x8, (u32x4){aw[0][0], aw[0][1], aw[0][2], aw[0][3]});
    bf16x8 pa1 = __builtin_bit_cast(bf16x8, (u32x4){aw[1][0], aw[1][1], aw[1][2], aw[1][3]});

    // ---- O += P @ V  (V via K-style swizzled ds_read_b128 from V2 tile) ----
    __builtin_amdgcn_s_setprio(1);
    #pragma unroll
    for (int n = 0; n < 4; ++n) {
      #pragma unroll
      for (int kk = 0; kk < 2; ++kk) {
        int d = n * 16 + q15;
        int kblk = kk * 4 + g;
        bf16x8 vb = *(const bf16x8*)(Vs[cur] + d * 64 + ((kblk ^ (d & 7)) << 3));
        acc_o[n] = MFMA16(kk ? pa1 : pa0, vb, acc_o[n]);
      }
    }
    __builtin_amdgcn_s_setprio(0);
    __syncthreads();
  }

  // ---- epilogue: O /= l, write bf16 to [B*C, H] ----
  float invl = 1.0f / l_run;
  float invj[4];
  #pragma unroll
  for (int j = 0; j < 4; ++j) invj[j] = __shfl(invl, 4 * g + j);
  #pragma unroll
  for (int n = 0; n < 4; ++n)
    #pragma unroll
    for (int j = 0; j < 4; ++j) {
      int qg = qt * 64 + w * 16 + 4 * g + j;
      Ob[((size_t)(bb * 2048 + qg)) * 1024 + h * 64 + n * 16 + q15] =
          f2bf(acc_o[n][j] * invj[j]);
    }
}

// grid = 32 heads x 16 balanced pairs; block handles q-tiles (31-p, p): 33 KV tiles.
__global__ __launch_bounds__(256, 4) void attn_kernel(
    const u16* __restrict__ Qb, const u16* __restrict__ Kb, const u16* __restrict__ V2b,
    u16* __restrict__ Ob) {
  __shared__ __align__(16) u16 Ks[2][64 * 64];
  __shared__ __align__(16) u16 Vs[2][64 * 64];
  const int blk = blockIdx.x;
  const int p = blk & 15;
  const int bh = blk >> 4;             // 0..31 (b*16+h)
  const size_t base = (size_t)bh * 2048 * 64;   // 32 tiles * 4096 = 2048*64
  const int bb = bh >> 4, h = bh & 15;
  attn_one(Qb + base, Kb + base, V2b + base, Ob, bb, h, 31 - p, Ks, Vs);
  attn_one(Qb + base, Kb + base, V2b + base, Ob, bb, h, p, Ks, Vs);
}

// ---------- launch ----------
extern "C" void kernel_launch(void* const* d_in, const int* in_sizes, int n_in,
                              void* d_out, int out_size, void* d_ws, size_t ws_size,
                              hipStream_t stream) {
  const float* x    = (const float*)d_in[0];   // [2,2048,1024]
  const float* wqkv = (const float*)d_in[1];   // [3072,1024]
  const float* bqkv = (const float*)d_in[2];   // [3072]
  const float* wo   = (const float*)d_in[3];   // [1024,1024]
  const float* bo   = (const float*)d_in[4];   // [1024]
  float* out = (float*)d_out;                  // [4096,1024] fp32

  const size_t MB = 1u << 20;
  char* ws = (char*)d_ws;
  u16* x_bf  = (u16*)(ws);             // 8 MB
  u16* wq_bf = (u16*)(ws + 8 * MB);    // 6 MB
  u16* wo_bf = (u16*)(ws + 14 * MB);   // 2 MB
  u16* q_buf = (u16*)(ws + 16 * MB);   // 8 MB  [B,nh,C,64]
  u16* k_buf = (u16*)(ws + 24 * MB);   // 8 MB  [B,nh,C,64]
  u16* v2_buf= (u16*)(ws + 32 * MB);   // 8 MB  [B,nh,tile32,d64,key64]
  u16* a_out = (u16*)(ws + 40 * MB);   // 8 MB  [4096,1024]

  cast_all_kernel<<<8192, 256, 0, stream>>>(x, wqkv, wo, x_bf, wq_bf, wo_bf);

  gemm_qkv_kernel<<<dim3(12, 16), 512, 0, stream>>>(x_bf, wq_bf, bqkv,
                                                    q_buf, k_buf, v2_buf);
  attn_kernel<<<512, 256, 0, stream>>>(q_buf, k_buf, v2_buf, a_out);
  gemm_out_kernel<<<dim3(8, 64), 256, 0, stream>>>(a_out, wo_bf, bo, out);
}